// Round 12
// baseline (91.122 us; speedup 1.0000x reference)
//
#include <hip/hip_runtime.h>

// S4D via chunked MFMA reformulation (R11 = exact revert to R9, verified
// best: 90.4 us, absmax 0.125).
//
//  y[c*64+t] = sum_j k[t-j]*x[c*64+j]              (lower-tri Toeplitz, local)
//            + Re( sum_n Ceff2_n w_n^{t+1} S_n[c] ) (carry from prior chunks)
//  S_n[c]    = w^64 * S_n[c-1] + V_n[c-1],  V_n[c] = sum_j w_n^{63-j} x[c*64+j]
//
//  prep : block = h, 256 threads; fully parallel matrix build, coalesced
//    b128 stores; also emits Earr = w^64.
//  fused: per (h, b-half) block, 4 waves x 32 (b,c) cols. The 5 per-h bf16
//    matrices are staged global->LDS ONCE per block (16B coalesced) and MFMA
//    B-fragments come from ds_read_b128 (removes ~62 MB of per-wave L2
//    re-reads; R7/R9 established ~0.13 us/MB on that path). W region rows
//    padded to 72 ushorts (144 B). Region reused: W1r/W1i (phase A) ->
//    TL/W2r/W2i (phase C).
//    A: MFMA V=X*W1^T -> packed LDS (stride-68, 2-way free);
//    B: reg-prefetched in-LDS scan -> r/i ushort planes;
//    C: y = Xhi*TL + Xlo*TL + Sr*W2r + Si*W2i, relu, coalesced store.
//
//  NOTE (R10 post-mortem): building W1 in-block instead of round-tripping
//  through global FAILED correctness (absmax 1.31) for reasons not explained
//  by inspection — do not retry without a device-side diff of the W1 bits.

#define B_ 8
#define H_ 256
#define N_ 64
#define L_ 2048
#define Q_ 64
#define NC_ 32
#define COLS_ 128
#define PKSTR_ 68      // packed V row stride (uints)
#define PLSTR_ 72      // plane / W-region row stride (ushorts); 144 B rows

typedef __attribute__((ext_vector_type(8))) short bf16x8;
typedef __attribute__((ext_vector_type(4))) float f32x4;

// ---- ws layout (bytes): 5 bf16 matrices (2 MiB each) + Earr ----
#define WS_W1R  0
#define WS_W1I  (WS_W1R + 2097152)
#define WS_TL   (WS_W1I + 2097152)
#define WS_W2R  (WS_TL  + 2097152)
#define WS_W2I  (WS_W2R + 2097152)
#define WS_E    (WS_W2I + 2097152)    // float2[256*64] = 128 KiB

#if defined(__has_builtin)
#  if __has_builtin(__builtin_amdgcn_cvt_pk_bf16_f32)
#    define HAVE_CVT_PK 1
#  endif
#endif

__device__ __forceinline__ unsigned short bf16_rne(float f) {
    unsigned int u = __float_as_uint(f);
    u += 0x7FFF + ((u >> 16) & 1);
    return (unsigned short)(u >> 16);
}
__device__ __forceinline__ float bf16_to_f(unsigned short h) {
    return __uint_as_float(((unsigned int)h) << 16);
}
// pack two floats to bf16x2 (a -> low, b -> high), RNE
__device__ __forceinline__ unsigned int pack_bf16x2(float a, float b) {
#ifdef HAVE_CVT_PK
    typedef __bf16 bf16v2 __attribute__((ext_vector_type(2)));
    bf16v2 p = __builtin_amdgcn_cvt_pk_bf16_f32(a, b);
    return __builtin_bit_cast(unsigned int, p);
#else
    unsigned int ua = __float_as_uint(a);
    ua += 0x7FFF + ((ua >> 16) & 1);
    unsigned int ub = __float_as_uint(b);
    ub += 0x7FFF + ((ub >> 16) & 1);
    return (ua >> 16) | (ub & 0xFFFF0000u);
#endif
}

// ================= prep (wide): per-h parameter matrices =================
__global__ __launch_bounds__(256) void s4d_prep(
    const float* __restrict__ A_real, const float* __restrict__ A_imag,
    const float* __restrict__ Bmat, const float* __restrict__ Cmat,
    const float* __restrict__ inv_dt,
    unsigned short* __restrict__ W1sr, unsigned short* __restrict__ W1si,
    unsigned short* __restrict__ TLs,
    unsigned short* __restrict__ W2sr, unsigned short* __restrict__ W2si,
    float2* __restrict__ Earr)
{
    __shared__ float qr_l[65 * 66];     // q[m][n] = Re(Ceff2 * w^m)
    __shared__ float qi_l[65 * 66];     // Im(...)
    __shared__ float klds[64];

    const int h   = blockIdx.x;
    const int tid = threadIdx.x;
    const int n   = tid >> 2;           // 0..63
    const int blk = tid & 3;            // 16-element column block
    const int hn  = h * N_ + n;

    // per-n params (computed redundantly by 4 threads; avoids communication)
    const float Ar = -expf(A_real[hn]);     // A = -exp(A_real) - i*A_imag
    const float Ai = -A_imag[hn];
    const float dtv = expf(inv_dt[h]);
    const float dr = dtv * Ar;
    const float di = dtv * Ai;
    const float ew = expf(dr);
    float sdi, cdi;
    sincosf(di, &sdi, &cdi);
    const float wr = ew * cdi;              // w = exp(dt*A)
    const float wi = ew * sdi;
    const float em1r = wr - 1.0f;           // (w-1)/A
    const float em1i = wi;
    const float invden = 1.0f / (Ar * Ar + Ai * Ai);
    const float tr = (em1r * Ar + em1i * Ai) * invden;
    const float ti = (em1i * Ar - em1r * Ai) * invden;
    const float br = Bmat[2 * hn], bi = Bmat[2 * hn + 1];
    const float cr = Cmat[2 * hn], ci = Cmat[2 * hn + 1];
    const float bcr = br * cr - bi * ci;
    const float bci = br * ci + bi * cr;
    const float Cr = 2.0f * (bcr * tr - bci * ti);   // Ceff2 = 2*B*C*(w-1)/A
    const float Ci = 2.0f * (bcr * ti + bci * tr);

    // ---- W1s[n][j] = w^(63-j), j in [16*blk, 16*blk+16) ----
    {
        const int m0 = 48 - 16 * blk;        // lowest m of this j-block
        const float e0 = expf((float)m0 * dr);
        float s0, c0;
        sincosf((float)m0 * di, &s0, &c0);
        float pr = e0 * c0, pi = e0 * s0;    // w^m0
        union { unsigned short u16[16]; uint4 q[2]; } tr_, ti_;
        #pragma unroll
        for (int i = 0; i < 16; ++i) {       // m = m0+i -> local j = 15-i
            tr_.u16[15 - i] = bf16_rne(pr);
            ti_.u16[15 - i] = bf16_rne(pi);
            const float npr = pr * wr - pi * wi;
            pi = pr * wi + pi * wr;
            pr = npr;
        }
        uint4* d0 = (uint4*)(W1sr + (size_t)h * 4096 + n * 64 + blk * 16);
        d0[0] = tr_.q[0]; d0[1] = tr_.q[1];
        uint4* d1 = (uint4*)(W1si + (size_t)h * 4096 + n * 64 + blk * 16);
        d1[0] = ti_.q[0]; d1[1] = ti_.q[1];
    }

    // ---- q table: m in [17*blk, ...) (blk 3 covers 51..64) ----
    {
        const int m0   = blk * 17;
        const int mcnt = (blk == 3) ? 14 : 17;
        const float e0 = expf((float)m0 * dr);
        float s0, c0;
        sincosf((float)m0 * di, &s0, &c0);
        float pr = e0 * c0, pi = e0 * s0;    // w^m0
        for (int i = 0; i < mcnt; ++i) {
            const int m = m0 + i;
            qr_l[m * 66 + n] = Cr * pr - Ci * pi;
            qi_l[m * 66 + n] = Cr * pi + Ci * pr;
            const float npr = pr * wr - pi * wi;
            pi = pr * wi + pi * wr;
            pr = npr;
        }
    }
    __syncthreads();

    // ---- k[t] = sum_n qr[t][n];  Earr[n] = w_n^64 ----
    if (tid < 64) {
        float s = 0.0f;
        for (int j = 0; j < 64; ++j) s += qr_l[tid * 66 + j];
        klds[tid] = s;

        const int hn2 = h * N_ + tid;
        const float Ar2 = -expf(A_real[hn2]);
        const float Ai2 = -A_imag[hn2];
        const float e64 = expf(64.0f * dtv * Ar2);
        float s64, c64;
        sincosf(64.0f * dtv * (-Ai2) * -1.0f, &s64, &c64);  // 64*dt*Ai2
        Earr[hn2] = make_float2(e64 * c64, e64 * s64);
    }
    __syncthreads();

    // ---- TL[t][j] = (j<=t)?k[t-j]:0 and W2[t][n] from q[t+1][n] ----
    {
        const int t = tid >> 2;
        union { unsigned short u16[16]; uint4 q[2]; } a_, b_;
        #pragma unroll
        for (int i = 0; i < 16; ++i) {
            const int j = blk * 16 + i;
            const int d = t - j;
            a_.u16[i] = bf16_rne(d >= 0 ? klds[d >= 0 ? d : 0] : 0.0f);
        }
        uint4* dtl = (uint4*)(TLs + (size_t)h * 4096 + t * 64 + blk * 16);
        dtl[0] = a_.q[0]; dtl[1] = a_.q[1];

        #pragma unroll
        for (int i = 0; i < 16; ++i) {
            const int nn = blk * 16 + i;
            a_.u16[i] = bf16_rne(qr_l[(t + 1) * 66 + nn]);     // Re(Ceff2 w^{t+1})
            b_.u16[i] = bf16_rne(-qi_l[(t + 1) * 66 + nn]);    // -Im(...)
        }
        uint4* d2r = (uint4*)(W2sr + (size_t)h * 4096 + t * 64 + blk * 16);
        d2r[0] = a_.q[0]; d2r[1] = a_.q[1];
        uint4* d2i = (uint4*)(W2si + (size_t)h * 4096 + t * 64 + blk * 16);
        d2i[0] = b_.q[0]; d2i[1] = b_.q[1];
    }
}

// ================= fused: staged-W V-GEMM -> in-LDS scan -> y-GEMM =================
__global__ __launch_bounds__(256) void s4d_fused(
    const float* __restrict__ x,
    const float2* __restrict__ Earr,
    const unsigned short* __restrict__ W1sr, const unsigned short* __restrict__ W1si,
    const unsigned short* __restrict__ TLs,
    const unsigned short* __restrict__ W2sr, const unsigned short* __restrict__ W2si,
    float* __restrict__ out)
{
    // 0..36864      : packed V (128x68 uints = 34816 B) ALIASED with the two
    //                 state planes (2 x 128x72 ushorts); barriers separate.
    // 36864..64512  : W region, 3 slots x 64 rows x 72 ushorts (13824 ushorts).
    //                 Phase A: slot0=W1r slot1=W1i; phase C: TL/W2r/W2i.
    __shared__ char smem[64512];
    unsigned int*   vpk  = (unsigned int*)smem;
    unsigned short* spr  = (unsigned short*)smem;
    unsigned short* spi  = (unsigned short*)(smem + COLS_ * PLSTR_ * 2);
    unsigned short* wreg = (unsigned short*)(smem + COLS_ * PLSTR_ * 4);

    const int h     = blockIdx.x >> 1;
    const int bhalf = blockIdx.x & 1;
    const int tid   = threadIdx.x;
    const int lane  = tid & 63;
    const int wv    = tid >> 6;
    const int colw  = wv * 32;
    const int l15   = lane & 15;
    const int quad  = lane >> 4;

    // ---- stage phase-A matrices: W1r -> slot0, W1i -> slot1 (coalesced) ----
    {
        const unsigned short* s0 = W1sr + (size_t)h * 4096;
        const unsigned short* s1 = W1si + (size_t)h * 4096;
        #pragma unroll
        for (int rep = 0; rep < 2; ++rep) {
            const int idx = rep * 256 + tid;
            const int row = idx >> 3, c8 = (idx & 7) * 8;
            *(uint4*)(wreg + row * PLSTR_ + c8) = *(const uint4*)(s0 + idx * 8);
            *(uint4*)(wreg + 4608 + row * PLSTR_ + c8) = *(const uint4*)(s1 + idx * 8);
        }
    }

    // ---- x fragments, loaded ONCE (hi/lo bf16 split), reused in A and C ----
    bf16x8 xhi[2][2], xlo[2][2];
    #pragma unroll
    for (int mt = 0; mt < 2; ++mt) {
        const int bc = colw + mt * 16 + l15;
        const int b  = bhalf * 4 + (bc >> 5);
        const int c  = bc & 31;
        const float* xp = x + ((size_t)(b * H_ + h)) * L_ + c * Q_;
        #pragma unroll
        for (int kk = 0; kk < 2; ++kk) {
            const int j0 = kk * 32 + quad * 8;
            const float4 f0 = *(const float4*)(xp + j0);
            const float4 f1 = *(const float4*)(xp + j0 + 4);
            float f[8] = {f0.x, f0.y, f0.z, f0.w, f1.x, f1.y, f1.z, f1.w};
            union { unsigned int u[4]; bf16x8 v; } hi, lo;
            #pragma unroll
            for (int p = 0; p < 4; ++p) {
                const unsigned int hp = pack_bf16x2(f[2 * p], f[2 * p + 1]);
                hi.u[p] = hp;
                const float h0 = __uint_as_float(hp << 16);
                const float h1 = __uint_as_float(hp & 0xFFFF0000u);
                lo.u[p] = pack_bf16x2(f[2 * p] - h0, f[2 * p + 1] - h1);
            }
            xhi[mt][kk] = hi.v;
            xlo[mt][kk] = lo.v;
        }
    }

    // ---- E = w^64 for n = lane (precomputed in prep) ----
    const float2 E = Earr[h * N_ + lane];
    const float Er = E.x, Ei = E.y;

    __syncthreads();   // W1 staging visible

    // ---- phase A: V[(b,c)][n] = X * W1^T (complex) -> packed LDS ----
    {
        f32x4 accr[2][4], acci[2][4];
        #pragma unroll
        for (int a = 0; a < 2; ++a)
            #pragma unroll
            for (int b = 0; b < 4; ++b) { accr[a][b] = (f32x4)0.0f; acci[a][b] = (f32x4)0.0f; }

        #pragma unroll
        for (int nt = 0; nt < 4; ++nt) {
            const int n = nt * 16 + l15;
            bf16x8 brf[2], bif[2];
            #pragma unroll
            for (int kk = 0; kk < 2; ++kk) {
                const int j0 = kk * 32 + quad * 8;
                brf[kk] = *(const bf16x8*)(wreg + n * PLSTR_ + j0);
                bif[kk] = *(const bf16x8*)(wreg + 4608 + n * PLSTR_ + j0);
            }
            #pragma unroll
            for (int mt = 0; mt < 2; ++mt)
                #pragma unroll
                for (int kk = 0; kk < 2; ++kk) {
                    accr[mt][nt] = __builtin_amdgcn_mfma_f32_16x16x32_bf16(
                        xhi[mt][kk], brf[kk], accr[mt][nt], 0, 0, 0);
                    acci[mt][nt] = __builtin_amdgcn_mfma_f32_16x16x32_bf16(
                        xhi[mt][kk], bif[kk], acci[mt][nt], 0, 0, 0);
                }
        }

        // D layout: row=(quad*4+r) -> bc, col=l15 -> n
        #pragma unroll
        for (int mt = 0; mt < 2; ++mt)
            #pragma unroll
            for (int nt = 0; nt < 4; ++nt)
                #pragma unroll
                for (int r = 0; r < 4; ++r) {
                    const int bc = colw + mt * 16 + quad * 4 + r;
                    const int n  = nt * 16 + l15;
                    vpk[bc * PKSTR_ + n] =
                        pack_bf16x2(accr[mt][nt][r], acci[mt][nt][r]);
                }
    }
    __syncthreads();

    // ---- phase B: prefetch V -> stage TL/W2 -> barrier -> scan -> planes ----
    {
        unsigned int vv[NC_];
        const unsigned int* vp = &vpk[(wv * NC_) * PKSTR_ + lane];
        #pragma unroll
        for (int c = 0; c < NC_; ++c) vv[c] = vp[c * PKSTR_];

        // stage phase-C matrices over the W1 region (all A-reads done)
        {
            const unsigned short* s0 = TLs  + (size_t)h * 4096;
            const unsigned short* s1 = W2sr + (size_t)h * 4096;
            const unsigned short* s2 = W2si + (size_t)h * 4096;
            #pragma unroll
            for (int rep = 0; rep < 2; ++rep) {
                const int idx = rep * 256 + tid;
                const int row = idx >> 3, c8 = (idx & 7) * 8;
                *(uint4*)(wreg + row * PLSTR_ + c8) = *(const uint4*)(s0 + idx * 8);
                *(uint4*)(wreg + 4608 + row * PLSTR_ + c8) = *(const uint4*)(s1 + idx * 8);
                *(uint4*)(wreg + 9216 + row * PLSTR_ + c8) = *(const uint4*)(s2 + idx * 8);
            }
        }
        __syncthreads();                       // packed-V lifetime ends; staging visible

        float sr = 0.0f, si = 0.0f;
        unsigned short* pr = &spr[(wv * NC_) * PLSTR_ + lane];
        unsigned short* pi = &spi[(wv * NC_) * PLSTR_ + lane];
        #pragma unroll
        for (int c = 0; c < NC_; ++c) {
            const float vr = __uint_as_float(vv[c] << 16);
            const float vi = __uint_as_float(vv[c] & 0xFFFF0000u);
            const unsigned int sp2 = pack_bf16x2(sr, si);  // entering state
            pr[c * PLSTR_] = (unsigned short)(sp2 & 0xFFFFu);
            pi[c * PLSTR_] = (unsigned short)(sp2 >> 16);
            const float nsr = fmaf(Er, sr, fmaf(-Ei, si, vr));
            si = fmaf(Ei, sr, fmaf(Er, si, vi));
            sr = nsr;
        }
    }
    __syncthreads();

    // ---- phase C: y = Xhi*TL + Xlo*TL + Sr*W2r + Si*W2i, relu ----
    {
        // S fragments: plain b128 reads from planes (A-operand layout)
        bf16x8 sr8[2][2], si8[2][2];
        #pragma unroll
        for (int mt = 0; mt < 2; ++mt) {
            const int bc = colw + mt * 16 + l15;
            #pragma unroll
            for (int kk = 0; kk < 2; ++kk) {
                const int j0 = kk * 32 + quad * 8;
                sr8[mt][kk] = *(const bf16x8*)(&spr[bc * PLSTR_ + j0]);
                si8[mt][kk] = *(const bf16x8*)(&spi[bc * PLSTR_ + j0]);
            }
        }

        f32x4 acc[2][4];
        #pragma unroll
        for (int a = 0; a < 2; ++a)
            #pragma unroll
            for (int t = 0; t < 4; ++t) acc[a][t] = (f32x4)0.0f;

        #pragma unroll
        for (int tt = 0; tt < 4; ++tt) {
            const int t = tt * 16 + l15;
            bf16x8 btl[2], bwr[2], bwi[2];
            #pragma unroll
            for (int kk = 0; kk < 2; ++kk) {
                const int j0 = kk * 32 + quad * 8;
                btl[kk] = *(const bf16x8*)(wreg + t * PLSTR_ + j0);
                bwr[kk] = *(const bf16x8*)(wreg + 4608 + t * PLSTR_ + j0);
                bwi[kk] = *(const bf16x8*)(wreg + 9216 + t * PLSTR_ + j0);
            }
            #pragma unroll
            for (int mt = 0; mt < 2; ++mt)
                #pragma unroll
                for (int kk = 0; kk < 2; ++kk) {
                    acc[mt][tt] = __builtin_amdgcn_mfma_f32_16x16x32_bf16(
                        xhi[mt][kk], btl[kk], acc[mt][tt], 0, 0, 0);
                    acc[mt][tt] = __builtin_amdgcn_mfma_f32_16x16x32_bf16(
                        xlo[mt][kk], btl[kk], acc[mt][tt], 0, 0, 0);
                    acc[mt][tt] = __builtin_amdgcn_mfma_f32_16x16x32_bf16(
                        sr8[mt][kk], bwr[kk], acc[mt][tt], 0, 0, 0);
                    acc[mt][tt] = __builtin_amdgcn_mfma_f32_16x16x32_bf16(
                        si8[mt][kk], bwi[kk], acc[mt][tt], 0, 0, 0);
                }
        }

        // store y with relu; lanes 0..15 -> consecutive t (64B segments)
        #pragma unroll
        for (int mt = 0; mt < 2; ++mt)
            #pragma unroll
            for (int tt = 0; tt < 4; ++tt)
                #pragma unroll
                for (int r = 0; r < 4; ++r) {
                    const int bc = colw + mt * 16 + quad * 4 + r;
                    const int b  = bhalf * 4 + (bc >> 5);
                    const int c  = bc & 31;
                    const int t  = tt * 16 + l15;
                    out[((size_t)(b * H_ + h)) * L_ + c * Q_ + t] =
                        fmaxf(acc[mt][tt][r], 0.0f);
                }
    }
}

extern "C" void kernel_launch(void* const* d_in, const int* in_sizes, int n_in,
                              void* d_out, int out_size, void* d_ws, size_t ws_size,
                              hipStream_t stream) {
    const float* x      = (const float*)d_in[0];
    const float* A_real = (const float*)d_in[1];
    const float* A_imag = (const float*)d_in[2];
    const float* Bmat   = (const float*)d_in[3];
    const float* Cmat   = (const float*)d_in[4];
    const float* inv_dt = (const float*)d_in[5];
    float* out = (float*)d_out;

    char* ws = (char*)d_ws;
    unsigned short* W1sr = (unsigned short*)(ws + WS_W1R);
    unsigned short* W1si = (unsigned short*)(ws + WS_W1I);
    unsigned short* TLs  = (unsigned short*)(ws + WS_TL);
    unsigned short* W2sr = (unsigned short*)(ws + WS_W2R);
    unsigned short* W2si = (unsigned short*)(ws + WS_W2I);
    float2*         Earr = (float2*)(ws + WS_E);

    s4d_prep<<<dim3(H_), dim3(256), 0, stream>>>(
        A_real, A_imag, Bmat, Cmat, inv_dt, W1sr, W1si, TLs, W2sr, W2si, Earr);
    s4d_fused<<<dim3(H_ * 2), dim3(256), 0, stream>>>(
        x, Earr, W1sr, W1si, TLs, W2sr, W2si, out);
}